// Round 9
// baseline (3295.811 us; speedup 1.0000x reference)
//
#include <hip/hip_runtime.h>
#include <cstdint>
#include <cstddef>

#define S_LEN 256
#define BATCH 64
#define HID   1024
#define GATES 4096
#define NBLK  256
#define FLAG_STRIDE 32   // 32 uints = 128 B: one cache line per block's flag

typedef _Float16 h16;
typedef _Float16 h16x8 __attribute__((ext_vector_type(8)));
typedef _Float16 h16x4 __attribute__((ext_vector_type(4)));
typedef float    f32x4 __attribute__((ext_vector_type(4)));

// ---------------------------------------------------------------------------
// x fp32 -> fp16 (one pass)
// ---------------------------------------------------------------------------
__global__ __launch_bounds__(256)
void xconv_kernel(const float* __restrict__ x, h16* __restrict__ x16)
{
  const int n4 = S_LEN * BATCH * HID / 4;
  const int stride = gridDim.x * 256;
  for (int i = blockIdx.x * 256 + threadIdx.x; i < n4; i += stride) {
    f32x4 v = ((const f32x4*)x)[i];
    h16x4 o;
    o[0] = (h16)v[0]; o[1] = (h16)v[1]; o[2] = (h16)v[2]; o[3] = (h16)v[3];
    ((h16x4*)x16)[i] = o;
  }
}

// ---------------------------------------------------------------------------
// Flat one-hop grid barrier, no wbl2 (R8-proven), + s_sleep poll backoff:
//  - h-ring payload is sc1 write-through -> at L3 once vmcnt drains (the
//    __syncthreads() entry emits s_waitcnt vmcnt(0) per wave).
//  - relaxed flag store; threads 0..NBLK-1 poll one flag each WITH s_sleep(1)
//    backoff (cuts L3 poll request pressure ~10x).
//  - one ACQUIRE load per block afterwards -> buffer_inv (L1+L2) so next
//    step's plain cached ring/x loads refill fresh from L3.
// Monotone counters; flags zeroed per kernel_launch.
// ---------------------------------------------------------------------------
__device__ __forceinline__ void grid_barrier(unsigned* flags, int g, int wg)
{
  __syncthreads();                      // vmcnt drained: sc1 h-stores at L3
  const unsigned tgt = (unsigned)(g + 1);
  if (threadIdx.x == 0)
    __hip_atomic_store(&flags[wg * FLAG_STRIDE], tgt,
                       __ATOMIC_RELAXED, __HIP_MEMORY_SCOPE_AGENT);
  if (threadIdx.x < NBLK) {
    while (__hip_atomic_load(&flags[threadIdx.x * FLAG_STRIDE],
                             __ATOMIC_RELAXED, __HIP_MEMORY_SCOPE_AGENT) < tgt)
      __builtin_amdgcn_s_sleep(1);
  }
  __syncthreads();                      // all 256 flags observed by this block
  if (threadIdx.x == 0)
    (void)__hip_atomic_load(&flags[0], __ATOMIC_ACQUIRE,
                            __HIP_MEMORY_SCOPE_AGENT);   // buffer_inv only
  __syncthreads();
}

// ---------------------------------------------------------------------------
// Persistent 2-layer pipelined LSTM. 256 WGs x 512 thr (8 waves, 2/SIMD).
// WG wg: layer = wg>>7, owns hidden cols j0..j0+7 (32 gate-cols = 2 n-tiles).
// Wave w owns K-slice [w*256,(w+1)*256): waves 0-3 input part (x or h0),
// waves 4-7 hidden part (h_prev). Weights fp16 in 128KB LDS (loaded once).
// Step g: layer0 does t=g, layer1 does t=g-1.
// Ring data: plain cached loads (per-XCD L2 shares the fill; freshness via
// the barrier's buffer_inv). h output: staged in LDS across the 4 m-rounds,
// then written as 128 coalesced 8B sc1 write-through stores (never dirty L2).
// 8-way cross-wave K-reduce via 16KB XOR-swizzled LDS, 4 m-rounds of 16 rows.
// ---------------------------------------------------------------------------
__global__ __launch_bounds__(512, 1)
void lstm_persistent(const h16* __restrict__ x16,
                     const float* __restrict__ weight,
                     const float* __restrict__ bias,
                     h16* __restrict__ h0r,
                     h16* __restrict__ h1r,
                     unsigned* __restrict__ flags)
{
  __shared__ h16   wlds[65536];        // 128 KB: [8 w][2 n2][8 s][64 lane][8]
  __shared__ float plds[8][16][32];    // 16 KB
  __shared__ h16   hstage[64][8];      // 1 KB: h staging for coalesced store

  const int wg    = blockIdx.x;
  const int layer = wg >> 7;
  const int j0    = (wg & 127) * 8;
  const int tid   = threadIdx.x;
  const int wave  = tid >> 6, lane = tid & 63;
  const int l15   = lane & 15, l16 = lane >> 4;

  // ---- one-time: pack this WG's weight slice fp32->fp16 into LDS ----
  {
    const float* wsrc = weight + (size_t)layer * 2 * GATES * HID;
    for (int c = tid; c < 8192; c += 512) {   // c = ((w*2+n2)*8+s)*64 + ln
      const int ln = c & 63, s = (c >> 6) & 7, n2 = (c >> 9) & 1, w = c >> 10;
      const int lc  = n2 * 16 + (ln & 15);              // local col 0..31
      const int col = (lc >> 3) * HID + j0 + (lc & 7);  // global gate col
      const int k   = w * 256 + s * 32 + (ln >> 4) * 8; // global K
      const float* p = wsrc + (k < HID ? (size_t)0 : (size_t)GATES * HID)
                            + (size_t)col * HID + (k & (HID - 1));
      h16x8 v;
#pragma unroll
      for (int e = 0; e < 8; ++e) v[e] = (h16)p[e];
      *(h16x8*)&wlds[(size_t)c * 8] = v;
    }
  }
  // combined bias for this thread's j (threads 0-127 use it)
  float bc[4];
  {
    const int j = tid & 7;
#pragma unroll
    for (int gg = 0; gg < 4; ++gg) {
      const int col = gg * HID + j0 + j;
      bc[gg] = bias[(size_t)layer * 2 * GATES + col] +
               bias[(size_t)layer * 2 * GATES + GATES + col];
    }
  }
  float creg[4] = {0.f, 0.f, 0.f, 0.f};
  __syncthreads();

  for (int g = 0; g <= S_LEN; ++g) {
    const bool active = (layer == 0) ? (g < S_LEN) : (g >= 1);
    if (active) {
      const h16 *Alo, *Ahi;
      h16* Hout;
      if (layer == 0) {
        Alo  = x16 + (size_t)g * (BATCH * HID);
        Ahi  = h0r + (size_t)((g + 1) & 1) * (BATCH * HID);
        Hout = h0r + (size_t)(g & 1) * (BATCH * HID);
      } else {
        Alo  = h0r + (size_t)((g - 1) & 1) * (BATCH * HID);
        Ahi  = h1r + (size_t)(g & 1) * (BATCH * HID);
        Hout = h1r + (size_t)((g - 1) & 1) * (BATCH * HID);
      }
      const h16* Asrc = (wave < 4) ? Alo : Ahi;
      const int kb = (wave & 3) * 256;

      const h16* arow[4];
#pragma unroll
      for (int i = 0; i < 4; ++i)
        arow[i] = Asrc + (size_t)(i * 16 + l15) * HID + kb + l16 * 8;
      const h16* bb = wlds + (size_t)wave * 8192 + lane * 8;  // n2 stride 4096

      f32x4 acc[4][2];
#pragma unroll
      for (int i = 0; i < 4; ++i)
#pragma unroll
        for (int n2 = 0; n2 < 2; ++n2) acc[i][n2] = (f32x4)0.f;

#pragma unroll
      for (int s = 0; s < 8; ++s) {
        const h16x8 b0 = *(const h16x8*)(bb + s * 512);
        const h16x8 b1 = *(const h16x8*)(bb + 4096 + s * 512);
#pragma unroll
        for (int i = 0; i < 4; ++i) {
          const h16x8 a = *(const h16x8*)(arow[i] + s * 32);
          acc[i][0] = __builtin_amdgcn_mfma_f32_16x16x32_f16(a, b0, acc[i][0], 0, 0, 0);
          acc[i][1] = __builtin_amdgcn_mfma_f32_16x16x32_f16(a, b1, acc[i][1], 0, 0, 0);
        }
      }

      // ---- 8-way cross-wave reduce + activations, 4 m-rounds of 16 rows ----
#pragma unroll
      for (int i = 0; i < 4; ++i) {
#pragma unroll
        for (int n2 = 0; n2 < 2; ++n2)
#pragma unroll
          for (int q = 0; q < 4; ++q) {
            const int r = l16 * 4 + q;                        // 0..15
            const int colS = (n2 * 16 + l15) ^ ((r & 7) << 2);
            plds[wave][r][colS] = acc[i][n2][q];
          }
        __syncthreads();
        if (tid < 128) {
          const int r = tid >> 3, j = tid & 7;
          float gv[4];
#pragma unroll
          for (int gg = 0; gg < 4; ++gg) {
            const int colS = (gg * 8 + j) ^ ((r & 7) << 2);
            float s = bc[gg];
#pragma unroll
            for (int w = 0; w < 8; ++w) s += plds[w][r][colS];
            gv[gg] = s;
          }
          const float ig = 1.f / (1.f + __expf(-gv[0]));
          const float fg = 1.f / (1.f + __expf(-gv[1]));
          const float gt = 1.f - 2.f / (__expf(2.f * gv[2]) + 1.f);
          const float og = 1.f / (1.f + __expf(-gv[3]));
          const float cn = fg * creg[i] + ig * gt;
          creg[i] = cn;
          const float th = 1.f - 2.f / (__expf(2.f * cn) + 1.f);
          hstage[i * 16 + r][j] = (h16)(og * th);
        }
        __syncthreads();
      }

      // ---- coalesced h write: 128 x 8B sc1 write-through stores ----
      if (tid < 128) {
        const int row = tid >> 1, half = tid & 1;
        const unsigned long long v =
            *(const unsigned long long*)&hstage[row][half * 4];
        __hip_atomic_store(
            (unsigned long long*)&Hout[(size_t)row * HID + j0 + half * 4],
            v, __ATOMIC_RELAXED, __HIP_MEMORY_SCOPE_AGENT);
      }
    }
    grid_barrier(flags, g, wg);
  }
}

// ---------------------------------------------------------------------------
// out[m][cls] = h[m] . fc_w[cls] + fc_b[cls]. One wave per output.
// ---------------------------------------------------------------------------
__global__ __launch_bounds__(256)
void fc_kernel(const h16* __restrict__ h,
               const float* __restrict__ fw,
               const float* __restrict__ fb,
               float* __restrict__ out)
{
  const int gw = (blockIdx.x * blockDim.x + threadIdx.x) >> 6;
  const int lane = threadIdx.x & 63;
  if (gw >= BATCH * 10) return;
  const int m = gw / 10, cls = gw % 10;
  float s = 0.f;
  for (int k = lane; k < HID; k += 64)
    s += (float)h[(size_t)m * HID + k] * fw[(size_t)cls * HID + k];
#pragma unroll
  for (int off = 32; off; off >>= 1) s += __shfl_down(s, off);
  if (lane == 0) out[m * 10 + cls] = s + fb[cls];
}

// ---------------------------------------------------------------------------
extern "C" void kernel_launch(void* const* d_in, const int* in_sizes, int n_in,
                              void* d_out, int out_size, void* d_ws, size_t ws_size,
                              hipStream_t stream)
{
  const float* x      = (const float*)d_in[0];   // [256][64][1024]
  const float* weight = (const float*)d_in[1];   // [2][2][4096][1024]
  const float* bias   = (const float*)d_in[2];   // [2][2][4096]
  const float* fc_w   = (const float*)d_in[3];   // [10][1024]
  const float* fc_b   = (const float*)d_in[4];   // [10]
  float* out = (float*)d_out;                    // [64][10]

  auto align = [](size_t v) { return (v + 255) & ~(size_t)255; };
  const size_t flags_sz = (size_t)NBLK * FLAG_STRIDE * sizeof(unsigned); // 32 KB
  const size_t x16_sz  = (size_t)S_LEN * BATCH * HID * sizeof(h16);      // 32 MB
  const size_t ring_sz = (size_t)2 * BATCH * HID * sizeof(h16);          // 256 KB

  char* p = (char*)d_ws;
  unsigned* flags = (unsigned*)p; p += align(flags_sz);
  h16* x16 = (h16*)p; p += align(x16_sz);
  h16* h0r = (h16*)p; p += align(ring_sz);
  h16* h1r = (h16*)p; p += align(ring_sz);

  hipMemsetAsync(flags, 0, flags_sz, stream);
  hipMemsetAsync(h0r, 0, ring_sz, stream);
  hipMemsetAsync(h1r, 0, ring_sz, stream);

  xconv_kernel<<<dim3(2048), 256, 0, stream>>>(x, x16);

  lstm_persistent<<<dim3(NBLK), dim3(512), 0, stream>>>(
      x16, weight, bias, h0r, h1r, flags);

  // final h of top layer: t = 255 -> ring slot 1
  fc_kernel<<<dim3((BATCH * 10 * 64) / 256), 256, 0, stream>>>(
      h1r + (size_t)BATCH * HID, fc_w, fc_b, out);
}

// Round 10
// 2885.665 us; speedup vs baseline: 1.1421x; 1.1421x over previous
//
#include <hip/hip_runtime.h>
#include <cstdint>
#include <cstddef>

#define S_LEN 256
#define BATCH 64
#define HID   1024
#define GATES 4096
#define NBLK  256
#define FLAG_STRIDE 32     // 32 uints = 128 B: one cache line per flag
#define XCC_GETREG_IMM 6164  // id=20 (HW_REG_XCC_ID) | off 0<<6 | (4-1)<<11

typedef _Float16 h16;
typedef _Float16 h16x8 __attribute__((ext_vector_type(8)));
typedef _Float16 h16x4 __attribute__((ext_vector_type(4)));
typedef float    f32x4 __attribute__((ext_vector_type(4)));

// ---------------------------------------------------------------------------
// x fp32 -> fp16 (one pass)
// ---------------------------------------------------------------------------
__global__ __launch_bounds__(256)
void xconv_kernel(const float* __restrict__ x, h16* __restrict__ x16)
{
  const int n4 = S_LEN * BATCH * HID / 4;
  const int stride = gridDim.x * 256;
  for (int i = blockIdx.x * 256 + threadIdx.x; i < n4; i += stride) {
    f32x4 v = ((const f32x4*)x)[i];
    h16x4 o;
    o[0] = (h16)v[0]; o[1] = (h16)v[1]; o[2] = (h16)v[2]; o[3] = (h16)v[3];
    ((h16x4*)x16)[i] = o;
  }
}

// ---------------------------------------------------------------------------
// Ring loads: sc0 (SE scope) = bypass per-CU L1, allocate/hit shared L2.
// waitcnt inside the asm so outputs are genuinely ready at asm exit.
// ---------------------------------------------------------------------------
__device__ __forceinline__ void load4_sc0(const h16* p0, const h16* p1,
                                          const h16* p2, const h16* p3,
                                          h16x8& a0, h16x8& a1,
                                          h16x8& a2, h16x8& a3)
{
  asm volatile(
      "global_load_dwordx4 %0, %4, off sc0\n\t"
      "global_load_dwordx4 %1, %5, off sc0\n\t"
      "global_load_dwordx4 %2, %6, off sc0\n\t"
      "global_load_dwordx4 %3, %7, off sc0\n\t"
      "s_waitcnt vmcnt(0)"
      : "=&v"(a0), "=&v"(a1), "=&v"(a2), "=&v"(a3)
      : "v"(p0), "v"(p1), "v"(p2), "v"(p3)
      : "memory");
}

// ---------------------------------------------------------------------------
// Step barrier with per-XCD leader inv:
//  - every block relaxed-stores its padded flag (h payload already at L3:
//    sc1 write-through + the __syncthreads vmcnt drain).
//  - leader block (one per physical XCD): polls all 256 flags, issues the
//    ONE acquire (buffer_inv: drops stale L2 ring lines for the whole XCD),
//    fences vmcnt(0), then relay-stores invdone[xcd].
//  - non-leaders: poll invdone[xcd] only (their ring reads are sc0 so no L1
//    staleness; L2 freshness guaranteed by their leader's inv).
// ---------------------------------------------------------------------------
__device__ __forceinline__ void step_barrier(unsigned* flags, unsigned* invdone,
                                             int g, int wg, int xcc, int leader)
{
  __syncthreads();                    // vmcnt drained: sc1 h-stores at L3
  const unsigned e = (unsigned)(g + 2);   // epoch 1 reserved for claim barrier
  if (threadIdx.x == 0)
    __hip_atomic_store(&flags[wg * FLAG_STRIDE], e,
                       __ATOMIC_RELAXED, __HIP_MEMORY_SCOPE_AGENT);
  if (leader) {
    if (threadIdx.x < NBLK) {
      while (__hip_atomic_load(&flags[threadIdx.x * FLAG_STRIDE],
                               __ATOMIC_RELAXED, __HIP_MEMORY_SCOPE_AGENT) < e) {}
    }
    __syncthreads();
    if (threadIdx.x == 0) {
      (void)__hip_atomic_load(&flags[0], __ATOMIC_ACQUIRE,
                              __HIP_MEMORY_SCOPE_AGENT);   // buffer_inv (L2)
      asm volatile("s_waitcnt vmcnt(0)" ::: "memory");     // inv retired
      __hip_atomic_store(&invdone[xcc * FLAG_STRIDE], e,
                         __ATOMIC_RELAXED, __HIP_MEMORY_SCOPE_AGENT);
    }
    __syncthreads();
  } else {
    if (threadIdx.x == 0) {
      while (__hip_atomic_load(&invdone[xcc * FLAG_STRIDE],
                               __ATOMIC_RELAXED, __HIP_MEMORY_SCOPE_AGENT) < e) {}
    }
    __syncthreads();
  }
}

// ---------------------------------------------------------------------------
// Persistent 2-layer pipelined LSTM. 256 WGs x 512 thr (8 waves, 2/SIMD).
// WG wg: layer = wg>>7, owns hidden cols j0..j0+7 (32 gate-cols = 2 n-tiles).
// Wave w owns K-slice [w*256,(w+1)*256): waves 0-3 input part (x or h0),
// waves 4-7 hidden part (h_prev). Weights fp16 in 128KB LDS (loaded once).
// Step g: layer0 does t=g, layer1 does t=g-1.
// Ring reads: sc0 loads (L1-bypass, L2-shared). Ring writes: sc1
// write-through (never dirty in L2 -> no wbl2 anywhere). One L2 inv per XCD
// per step via the leader. x16/bias: plain cached (immutable during kernel).
// 8-way cross-wave K-reduce via 16KB XOR-swizzled LDS, 4 m-rounds of 16 rows.
// ---------------------------------------------------------------------------
__global__ __launch_bounds__(512, 1)
void lstm_persistent(const h16* __restrict__ x16,
                     const float* __restrict__ weight,
                     const float* __restrict__ bias,
                     h16* __restrict__ h0r,
                     h16* __restrict__ h1r,
                     unsigned* __restrict__ flags,
                     unsigned* __restrict__ claim,
                     unsigned* __restrict__ invdone)
{
  __shared__ h16   wlds[65536];        // 128 KB: [8 w][2 n2][8 s][64 lane][8]
  __shared__ float plds[8][16][32];    // 16 KB
  __shared__ int   lsh[2];             // [xcc, is_leader]

  const int wg    = blockIdx.x;
  const int layer = wg >> 7;
  const int j0    = (wg & 127) * 8;
  const int tid   = threadIdx.x;
  const int wave  = tid >> 6, lane = tid & 63;
  const int l15   = lane & 15, l16 = lane >> 4;

  // ---- one-time: pack this WG's weight slice fp32->fp16 into LDS ----
  {
    const float* wsrc = weight + (size_t)layer * 2 * GATES * HID;
    for (int c = tid; c < 8192; c += 512) {   // c = ((w*2+n2)*8+s)*64 + ln
      const int ln = c & 63, s = (c >> 6) & 7, n2 = (c >> 9) & 1, w = c >> 10;
      const int lc  = n2 * 16 + (ln & 15);              // local col 0..31
      const int col = (lc >> 3) * HID + j0 + (lc & 7);  // global gate col
      const int k   = w * 256 + s * 32 + (ln >> 4) * 8; // global K
      const float* p = wsrc + (k < HID ? (size_t)0 : (size_t)GATES * HID)
                            + (size_t)col * HID + (k & (HID - 1));
      h16x8 v;
#pragma unroll
      for (int e = 0; e < 8; ++e) v[e] = (h16)p[e];
      *(h16x8*)&wlds[(size_t)c * 8] = v;
    }
  }
  // combined bias for this thread's j (threads 0-127 use it)
  float bc[4];
  {
    const int j = tid & 7;
#pragma unroll
    for (int gg = 0; gg < 4; ++gg) {
      const int col = gg * HID + j0 + j;
      bc[gg] = bias[(size_t)layer * 2 * GATES + col] +
               bias[(size_t)layer * 2 * GATES + GATES + col];
    }
  }
  float creg[4] = {0.f, 0.f, 0.f, 0.f};

  // ---- one-time: leader election on physical XCD id (claim = last wins) ----
  if (tid == 0) {
    const int id = (int)(__builtin_amdgcn_s_getreg(XCC_GETREG_IMM) & 7u);
    lsh[0] = id;
    __hip_atomic_store(&claim[id * FLAG_STRIDE], (unsigned)(wg + 1),
                       __ATOMIC_RELAXED, __HIP_MEMORY_SCOPE_AGENT);
  }
  __syncthreads();                    // claim store drained (vmcnt)
  if (tid == 0)
    __hip_atomic_store(&flags[wg * FLAG_STRIDE], 1u,
                       __ATOMIC_RELAXED, __HIP_MEMORY_SCOPE_AGENT);
  if (tid < NBLK) {
    while (__hip_atomic_load(&flags[tid * FLAG_STRIDE],
                             __ATOMIC_RELAXED, __HIP_MEMORY_SCOPE_AGENT) < 1u) {}
  }
  __syncthreads();
  if (tid == 0) {
    const unsigned lw = __hip_atomic_load(&claim[lsh[0] * FLAG_STRIDE],
                                          __ATOMIC_RELAXED,
                                          __HIP_MEMORY_SCOPE_AGENT);
    lsh[1] = (lw == (unsigned)(wg + 1)) ? 1 : 0;
  }
  __syncthreads();
  const int xcc = lsh[0], is_leader = lsh[1];

  for (int g = 0; g <= S_LEN; ++g) {
    const bool active = (layer == 0) ? (g < S_LEN) : (g >= 1);
    if (active) {
      const h16 *Alo, *Ahi;
      h16* Hout;
      if (layer == 0) {
        Alo  = x16 + (size_t)g * (BATCH * HID);
        Ahi  = h0r + (size_t)((g + 1) & 1) * (BATCH * HID);
        Hout = h0r + (size_t)(g & 1) * (BATCH * HID);
      } else {
        Alo  = h0r + (size_t)((g - 1) & 1) * (BATCH * HID);
        Ahi  = h1r + (size_t)(g & 1) * (BATCH * HID);
        Hout = h1r + (size_t)((g - 1) & 1) * (BATCH * HID);
      }
      const h16* Asrc = (wave < 4) ? Alo : Ahi;
      const bool ring = (layer == 1) || (wave >= 4);   // wave-uniform
      const int kb = (wave & 3) * 256;

      const h16* arow[4];
#pragma unroll
      for (int i = 0; i < 4; ++i)
        arow[i] = Asrc + (size_t)(i * 16 + l15) * HID + kb + l16 * 8;
      const h16* bb = wlds + (size_t)wave * 8192 + lane * 8;  // n2 stride 4096

      f32x4 acc[4][2];
#pragma unroll
      for (int i = 0; i < 4; ++i)
#pragma unroll
        for (int n2 = 0; n2 < 2; ++n2) acc[i][n2] = (f32x4)0.f;

#pragma unroll
      for (int s = 0; s < 8; ++s) {
        const h16x8 b0 = *(const h16x8*)(bb + s * 512);
        const h16x8 b1 = *(const h16x8*)(bb + 4096 + s * 512);
        h16x8 a0, a1, a2, a3;
        if (ring) {
          load4_sc0(arow[0] + s * 32, arow[1] + s * 32,
                    arow[2] + s * 32, arow[3] + s * 32, a0, a1, a2, a3);
        } else {
          a0 = *(const h16x8*)(arow[0] + s * 32);
          a1 = *(const h16x8*)(arow[1] + s * 32);
          a2 = *(const h16x8*)(arow[2] + s * 32);
          a3 = *(const h16x8*)(arow[3] + s * 32);
        }
        acc[0][0] = __builtin_amdgcn_mfma_f32_16x16x32_f16(a0, b0, acc[0][0], 0, 0, 0);
        acc[0][1] = __builtin_amdgcn_mfma_f32_16x16x32_f16(a0, b1, acc[0][1], 0, 0, 0);
        acc[1][0] = __builtin_amdgcn_mfma_f32_16x16x32_f16(a1, b0, acc[1][0], 0, 0, 0);
        acc[1][1] = __builtin_amdgcn_mfma_f32_16x16x32_f16(a1, b1, acc[1][1], 0, 0, 0);
        acc[2][0] = __builtin_amdgcn_mfma_f32_16x16x32_f16(a2, b0, acc[2][0], 0, 0, 0);
        acc[2][1] = __builtin_amdgcn_mfma_f32_16x16x32_f16(a2, b1, acc[2][1], 0, 0, 0);
        acc[3][0] = __builtin_amdgcn_mfma_f32_16x16x32_f16(a3, b0, acc[3][0], 0, 0, 0);
        acc[3][1] = __builtin_amdgcn_mfma_f32_16x16x32_f16(a3, b1, acc[3][1], 0, 0, 0);
      }

      // ---- 8-way cross-wave reduce + activations, 4 m-rounds of 16 rows ----
#pragma unroll
      for (int i = 0; i < 4; ++i) {
#pragma unroll
        for (int n2 = 0; n2 < 2; ++n2)
#pragma unroll
          for (int q = 0; q < 4; ++q) {
            const int r = l16 * 4 + q;                        // 0..15
            const int colS = (n2 * 16 + l15) ^ ((r & 7) << 2);
            plds[wave][r][colS] = acc[i][n2][q];
          }
        __syncthreads();
        if (tid < 128) {
          const int r = tid >> 3, j = tid & 7;
          float gv[4];
#pragma unroll
          for (int gg = 0; gg < 4; ++gg) {
            const int colS = (gg * 8 + j) ^ ((r & 7) << 2);
            float s = bc[gg];
#pragma unroll
            for (int w = 0; w < 8; ++w) s += plds[w][r][colS];
            gv[gg] = s;
          }
          const float ig = 1.f / (1.f + __expf(-gv[0]));
          const float fg = 1.f / (1.f + __expf(-gv[1]));
          const float gt = 1.f - 2.f / (__expf(2.f * gv[2]) + 1.f);
          const float og = 1.f / (1.f + __expf(-gv[3]));
          const float cn = fg * creg[i] + ig * gt;
          creg[i] = cn;
          const float th = 1.f - 2.f / (__expf(2.f * cn) + 1.f);
          union { h16 f; unsigned short u; } hb;
          hb.f = (h16)(og * th);
          __hip_atomic_store(
              (unsigned short*)&Hout[(size_t)(i * 16 + r) * HID + j0 + j],
              hb.u, __ATOMIC_RELAXED, __HIP_MEMORY_SCOPE_AGENT);
        }
        __syncthreads();
      }
    }
    step_barrier(flags, invdone, g, wg, xcc, is_leader);
  }
}

// ---------------------------------------------------------------------------
// out[m][cls] = h[m] . fc_w[cls] + fc_b[cls]. One wave per output.
// ---------------------------------------------------------------------------
__global__ __launch_bounds__(256)
void fc_kernel(const h16* __restrict__ h,
               const float* __restrict__ fw,
               const float* __restrict__ fb,
               float* __restrict__ out)
{
  const int gw = (blockIdx.x * blockDim.x + threadIdx.x) >> 6;
  const int lane = threadIdx.x & 63;
  if (gw >= BATCH * 10) return;
  const int m = gw / 10, cls = gw % 10;
  float s = 0.f;
  for (int k = lane; k < HID; k += 64)
    s += (float)h[(size_t)m * HID + k] * fw[(size_t)cls * HID + k];
#pragma unroll
  for (int off = 32; off; off >>= 1) s += __shfl_down(s, off);
  if (lane == 0) out[m * 10 + cls] = s + fb[cls];
}

// ---------------------------------------------------------------------------
extern "C" void kernel_launch(void* const* d_in, const int* in_sizes, int n_in,
                              void* d_out, int out_size, void* d_ws, size_t ws_size,
                              hipStream_t stream)
{
  const float* x      = (const float*)d_in[0];   // [256][64][1024]
  const float* weight = (const float*)d_in[1];   // [2][2][4096][1024]
  const float* bias   = (const float*)d_in[2];   // [2][2][4096]
  const float* fc_w   = (const float*)d_in[3];   // [10][1024]
  const float* fc_b   = (const float*)d_in[4];   // [10]
  float* out = (float*)d_out;                    // [64][10]

  auto align = [](size_t v) { return (v + 255) & ~(size_t)255; };
  const size_t flags_sz = (size_t)NBLK * FLAG_STRIDE * sizeof(unsigned); // 32 KB
  const size_t aux_sz   = (size_t)8 * FLAG_STRIDE * sizeof(unsigned);    // 1 KB
  const size_t x16_sz  = (size_t)S_LEN * BATCH * HID * sizeof(h16);      // 32 MB
  const size_t ring_sz = (size_t)2 * BATCH * HID * sizeof(h16);          // 256 KB

  char* p = (char*)d_ws;
  unsigned* flags   = (unsigned*)p; p += align(flags_sz);
  unsigned* claim   = (unsigned*)p; p += align(aux_sz);
  unsigned* invdone = (unsigned*)p; p += align(aux_sz);
  h16* x16 = (h16*)p; p += align(x16_sz);
  h16* h0r = (h16*)p; p += align(ring_sz);
  h16* h1r = (h16*)p; p += align(ring_sz);

  hipMemsetAsync(flags, 0, flags_sz, stream);
  hipMemsetAsync(claim, 0, aux_sz, stream);
  hipMemsetAsync(invdone, 0, aux_sz, stream);
  hipMemsetAsync(h0r, 0, ring_sz, stream);
  hipMemsetAsync(h1r, 0, ring_sz, stream);

  xconv_kernel<<<dim3(2048), 256, 0, stream>>>(x, x16);

  lstm_persistent<<<dim3(NBLK), dim3(512), 0, stream>>>(
      x16, weight, bias, h0r, h1r, flags, claim, invdone);

  // final h of top layer: t = 255 -> ring slot 1
  fc_kernel<<<dim3((BATCH * 10 * 64) / 256), 256, 0, stream>>>(
      h1r + (size_t)BATCH * HID, fc_w, fc_b, out);
}